// Round 1
// baseline (1875.905 us; speedup 1.0000x reference)
//
#include <hip/hip_runtime.h>
#include <hip/hip_cooperative_groups.h>

namespace cg = cooperative_groups;

// x: [B=2, C=3, D=128, H=160, W=160] fp32, num_steps=6
#define BB 2
#define DD 128
#define HH 160
#define WW 160
constexpr int S   = DD * HH * WW;    // voxels per batch   = 3,276,800
constexpr int PL  = HH * WW;         // plane (h*w)        = 25,600
constexpr int VPB = 1024;            // voxels per tile (4 per thread)
constexpr int TPP = PL / VPB;        // 25 tiles per plane
constexpr int NT  = BB * DD * TPP;   // 6400 tiles
constexpr int PER_XCD = NT / 8;      // 800 tiles -> 32 contiguous planes per XCD
constexpr int GRID = 1280;           // 5 blocks/CU exactly; NT/GRID = 5 exactly

// 12-byte, 4-aligned record: guarantees a single global_load/store_dwordx3
struct __attribute__((packed, aligned(4))) f3 { float x, y, z; };

__device__ __forceinline__ int warp_index(int d, int h, int w,
                                          float f0, float f1, float f2) {
    // round-half-to-even (jnp.round == rintf), clamp per-dim
    int id = (int)fminf(fmaxf(rintf((float)d + f0), 0.0f), (float)(DD - 1));
    int ih = (int)fminf(fmaxf(rintf((float)h + f1), 0.0f), (float)(HH - 1));
    int iw = (int)fminf(fmaxf(rintf((float)w + f2), 0.0f), (float)(WW - 1));
    return (id * HH + ih) * WW + iw;
}

// One 1024-voxel tile of one squaring pass. IN_SOA: read [3,S] (input x, fused /64).
// OUT_SOA: write [3,S] (final out). Otherwise tight 12 B AoS [S,3].
template <bool IN_SOA, bool OUT_SOA>
__device__ __forceinline__ void do_tile(const float* __restrict__ vin,
                                        float* __restrict__ vout,
                                        float scale, int t, int tid) {
    // XCD slab swizzle: tiles with (t&7)==x belong to XCD x's contiguous slab.
    int nb  = (t >> 3) + (t & 7) * PER_XCD;
    int b   = nb / (DD * TPP);
    int r   = nb - b * (DD * TPP);
    int d   = r / TPP;
    int ipb = (r - d * TPP) * VPB + tid;   // voxel-in-plane for k=0

    float a[4][3];
    int   p[4], q[4];
    // --- 4 center reads issued back-to-back (MLP) ---
#pragma unroll
    for (int k = 0; k < 4; ++k) {
        int ip = ipb + k * 256;
        p[k] = d * PL + ip;
        if constexpr (IN_SOA) {
            int s = b * 3 * S + p[k];
            a[k][0] = vin[s] * scale;
            a[k][1] = vin[s + S] * scale;
            a[k][2] = vin[s + 2 * S] * scale;
        } else {
            f3 v = *(const f3*)(vin + (b * S + p[k]) * 3);
            a[k][0] = v.x; a[k][1] = v.y; a[k][2] = v.z;
        }
    }
    // --- 4 index computations ---
#pragma unroll
    for (int k = 0; k < 4; ++k) {
        int ip = ipb + k * 256;
        int w = ip % WW, h = ip / WW;
        q[k] = warp_index(d, h, w, a[k][0], a[k][1], a[k][2]);
    }
    // --- 4 independent gather chains ---
    float g[4][3];
#pragma unroll
    for (int k = 0; k < 4; ++k) {
        if constexpr (IN_SOA) {
            int s = b * 3 * S + q[k];
            g[k][0] = vin[s] * scale;
            g[k][1] = vin[s + S] * scale;
            g[k][2] = vin[s + 2 * S] * scale;
        } else {
            f3 v = *(const f3*)(vin + (b * S + q[k]) * 3);
            g[k][0] = v.x; g[k][1] = v.y; g[k][2] = v.z;
        }
    }
    // --- stores ---
#pragma unroll
    for (int k = 0; k < 4; ++k) {
        if constexpr (OUT_SOA) {
            int s = b * 3 * S + p[k];
            vout[s]         = a[k][0] + g[k][0];
            vout[s + S]     = a[k][1] + g[k][1];
            vout[s + 2 * S] = a[k][2] + g[k][2];
        } else {
            f3 v{a[k][0] + g[k][0], a[k][1] + g[k][1], a[k][2] + g[k][2]};
            *(f3*)(vout + (b * S + p[k]) * 3) = v;
        }
    }
}

// All 6 passes in one cooperative kernel. 1280 blocks = 5/CU exactly; each block
// owns exactly 5 tiles per pass (NT/GRID), all within its XCD's slab, all passes.
__global__ __launch_bounds__(256, 5) void fused_k(const float* __restrict__ x,
                                                  float* __restrict__ ws,
                                                  float* __restrict__ out) {
    cg::grid_group grid = cg::this_grid();
    const int tid = threadIdx.x;
    const int bid = blockIdx.x;

    for (int t = bid; t < NT; t += GRID) do_tile<true,  false>(x,   ws,  1.0f / 64.0f, t, tid);
    __threadfence(); grid.sync();
    for (int t = bid; t < NT; t += GRID) do_tile<false, false>(ws,  out, 1.0f, t, tid);
    __threadfence(); grid.sync();
    for (int t = bid; t < NT; t += GRID) do_tile<false, false>(out, ws,  1.0f, t, tid);
    __threadfence(); grid.sync();
    for (int t = bid; t < NT; t += GRID) do_tile<false, false>(ws,  out, 1.0f, t, tid);
    __threadfence(); grid.sync();
    for (int t = bid; t < NT; t += GRID) do_tile<false, false>(out, ws,  1.0f, t, tid);
    __threadfence(); grid.sync();
    for (int t = bid; t < NT; t += GRID) do_tile<false, true >(ws,  out, 1.0f, t, tid);
}

// Fallback (non-cooperative): one pass per launch, one tile per block.
template <bool IN_SOA, bool OUT_SOA>
__global__ __launch_bounds__(256) void pass_k(const float* __restrict__ vin,
                                              float* __restrict__ vout,
                                              float scale) {
    for (int t = blockIdx.x; t < NT; t += gridDim.x)
        do_tile<IN_SOA, OUT_SOA>(vin, vout, scale, t, threadIdx.x);
}

extern "C" void kernel_launch(void* const* d_in, const int* in_sizes, int n_in,
                              void* d_out, int out_size, void* d_ws, size_t ws_size,
                              hipStream_t stream) {
    const float* x = (const float*)d_in[0];
    float* out = (float*)d_out;     // 78,643,200 bytes — final SoA result
    float* ws  = (float*)d_ws;      // >= 78,643,200 bytes (tight AoS intermediate)

    void* args[] = { (void*)&x, (void*)&ws, (void*)&out };
    hipError_t err = hipLaunchCooperativeKernel((const void*)fused_k,
                                                dim3(GRID), dim3(256),
                                                args, 0, stream);
    if (err != hipSuccess) {
        // Cooperative launch unavailable: 6 separate passes, same tile code.
        pass_k<true,  false><<<NT, 256, 0, stream>>>(x,   ws,  1.0f / 64.0f);
        pass_k<false, false><<<NT, 256, 0, stream>>>(ws,  out, 1.0f);
        pass_k<false, false><<<NT, 256, 0, stream>>>(out, ws,  1.0f);
        pass_k<false, false><<<NT, 256, 0, stream>>>(ws,  out, 1.0f);
        pass_k<false, false><<<NT, 256, 0, stream>>>(out, ws,  1.0f);
        pass_k<false, true ><<<NT, 256, 0, stream>>>(ws,  out, 1.0f);
    }
}

// Round 2
// 273.818 us; speedup vs baseline: 6.8509x; 6.8509x over previous
//
#include <hip/hip_runtime.h>

// x: [B=2, C=3, D=128, H=160, W=160] fp32, num_steps=6
#define BB 2
#define DD 128
#define HH 160
#define WW 160
constexpr int S   = DD * HH * WW;    // voxels per batch   = 3,276,800
constexpr int PL  = HH * WW;         // plane (h*w)        = 25,600
constexpr int K   = 4;               // voxels per thread (4 independent gather chains)
constexpr int VPB = 256 * K;         // 1024 voxels per block
constexpr int TPP = PL / VPB;        // 25 tiles per plane
constexpr int NT  = BB * DD * TPP;   // 6400 blocks
constexpr int PER_XCD = NT / 8;      // 800 -> 32 contiguous d-planes per XCD

// 12-byte, 4-aligned record: single dwordx3 load/store
struct __attribute__((packed, aligned(4))) f3 { float x, y, z; };

// clamp(round(base + flow)) per dim; returns clamped coords + linear index
__device__ __forceinline__ void clamp_idx(int d, int h, int w,
                                          float f0, float f1, float f2,
                                          int& od, int& oh, int& ow, int& lin) {
    od = (int)fminf(fmaxf(rintf((float)d + f0), 0.0f), (float)(DD - 1));
    oh = (int)fminf(fmaxf(rintf((float)h + f1), 0.0f), (float)(HH - 1));
    ow = (int)fminf(fmaxf(rintf((float)w + f2), 0.0f), (float)(WW - 1));
    lin = (od * HH + oh) * WW + ow;
}

template <bool SOA>
__device__ __forceinline__ void load3(const float* __restrict__ v, int b, int idx,
                                      float scale, float* o) {
    if constexpr (SOA) {
        int s = b * 3 * S + idx;
        o[0] = v[s] * scale; o[1] = v[s + S] * scale; o[2] = v[s + 2 * S] * scale;
    } else {
        f3 t = *(const f3*)(v + (b * S + idx) * 3);
        o[0] = t.x; o[1] = t.y; o[2] = t.z;
    }
}

// TWO squaring steps fused:  v''(p) = v'(p) + v'(r'(p)),  v'(q) = v(q) + v(r(q)).
// Loads: v(p) [stream], v(r0), v(r1), v(r2) [gathers]; 1 store. Staged K-wide for MLP.
// Addition grouping matches the reference exactly (bit-exact).
template <bool IN_SOA, bool OUT_SOA>
__global__ __launch_bounds__(256) void fused2_k(const float* __restrict__ vin,
                                                float* __restrict__ vout,
                                                float scale) {
    // XCD-aware swizzle: each XCD owns a contiguous 1/8 slab (32 d-planes).
    int t  = blockIdx.x;
    int nb = (t >> 3) + (t & 7) * PER_XCD;
    int b  = nb / (DD * TPP);
    int r  = nb - b * (DD * TPP);
    int d  = r / TPP;
    int ip0 = (r - d * TPP) * VPB + threadIdx.x;

    int   p[K], h[K], w[K];
    float a[K][3];
    // --- stage 1: K center reads (coalesced), back-to-back ---
#pragma unroll
    for (int k = 0; k < K; ++k) {
        int ip = ip0 + k * 256;
        w[k] = ip % WW; h[k] = ip / WW;
        p[k] = d * PL + ip;
        load3<IN_SOA>(vin, b, p[k], scale, a[k]);
    }
    // --- stage 2: r0 = clamp(round(p + v(p))) ; gather g = v(r0) ---
    int r0i[K];
#pragma unroll
    for (int k = 0; k < K; ++k) {
        int rd, rh, rw;
        clamp_idx(d, h[k], w[k], a[k][0], a[k][1], a[k][2], rd, rh, rw, r0i[k]);
    }
    float g[K][3];
#pragma unroll
    for (int k = 0; k < K; ++k) load3<IN_SOA>(vin, b, r0i[k], scale, g[k]);
    // --- stage 3: v1 = v'(p) = a + g ; r1 = clamp(round(p + v1)) ---
    float v1[K][3];
    int r1d[K], r1h[K], r1w[K], r1i[K];
#pragma unroll
    for (int k = 0; k < K; ++k) {
        v1[k][0] = a[k][0] + g[k][0];
        v1[k][1] = a[k][1] + g[k][1];
        v1[k][2] = a[k][2] + g[k][2];
        clamp_idx(d, h[k], w[k], v1[k][0], v1[k][1], v1[k][2],
                  r1d[k], r1h[k], r1w[k], r1i[k]);
    }
    // --- stage 4: bb = v(r1) ---
    float bb[K][3];
#pragma unroll
    for (int k = 0; k < K; ++k) load3<IN_SOA>(vin, b, r1i[k], scale, bb[k]);
    // --- stage 5: r2 = clamp(round(r1 + v(r1))) ; h2 = v(r2) ---
    int r2i[K];
#pragma unroll
    for (int k = 0; k < K; ++k) {
        int rd, rh, rw;
        clamp_idx(r1d[k], r1h[k], r1w[k], bb[k][0], bb[k][1], bb[k][2],
                  rd, rh, rw, r2i[k]);
    }
    float h2[K][3];
#pragma unroll
    for (int k = 0; k < K; ++k) load3<IN_SOA>(vin, b, r2i[k], scale, h2[k]);
    // --- stage 6: out = v1 + (bb + h2)   [= v'(p) + v'(r1), ref grouping] ---
#pragma unroll
    for (int k = 0; k < K; ++k) {
        float o0 = v1[k][0] + (bb[k][0] + h2[k][0]);
        float o1 = v1[k][1] + (bb[k][1] + h2[k][1]);
        float o2 = v1[k][2] + (bb[k][2] + h2[k][2]);
        if constexpr (OUT_SOA) {
            int s = b * 3 * S + p[k];
            vout[s] = o0; vout[s + S] = o1; vout[s + 2 * S] = o2;
        } else {
            f3 v{o0, o1, o2};
            *(f3*)(vout + (b * S + p[k]) * 3) = v;
        }
    }
}

extern "C" void kernel_launch(void* const* d_in, const int* in_sizes, int n_in,
                              void* d_out, int out_size, void* d_ws, size_t ws_size,
                              hipStream_t stream) {
    const float* x = (const float*)d_in[0];
    float* out = (float*)d_out;     // 78,643,200 bytes — doubles as AoS intermediate
    float* ws  = (float*)d_ws;      // >= 78,643,200 bytes (tight AoS)

    // 3 fused passes (2 squaring steps each), ping-pong so the last lands in out.
    fused2_k<true,  false><<<NT, 256, 0, stream>>>(x,   out, 1.0f / 64.0f); // steps 1-2
    fused2_k<false, false><<<NT, 256, 0, stream>>>(out, ws,  1.0f);         // steps 3-4
    fused2_k<false, true ><<<NT, 256, 0, stream>>>(ws,  out, 1.0f);         // steps 5-6
}

// Round 3
// 251.293 us; speedup vs baseline: 7.4650x; 1.0896x over previous
//
#include <hip/hip_runtime.h>

// x: [B=2, C=3, D=128, H=160, W=160] fp32, num_steps=6
#define BB 2
#define DD 128
#define HH 160
#define WW 160
constexpr int S   = DD * HH * WW;    // voxels per batch   = 3,276,800
constexpr int PL  = HH * WW;         // plane (h*w)        = 25,600
constexpr int K   = 4;               // voxels per thread (4 independent gather chains)
constexpr int VPB = 256 * K;         // 1024 voxels per block
constexpr int TPP = PL / VPB;        // 25 tiles per plane
constexpr int NT  = BB * DD * TPP;   // 6400 blocks
constexpr int PER_XCD = NT / 8;      // 800 -> 32 contiguous d-planes per XCD

// 12-byte, 4-aligned record: single dwordx3 load/store
struct __attribute__((packed, aligned(4))) f3 { float x, y, z; };

// clamp(round(base + flow)) per dim; returns clamped coords + linear index
__device__ __forceinline__ void clamp_idx(int d, int h, int w,
                                          float f0, float f1, float f2,
                                          int& od, int& oh, int& ow, int& lin) {
    od = (int)fminf(fmaxf(rintf((float)d + f0), 0.0f), (float)(DD - 1));
    oh = (int)fminf(fmaxf(rintf((float)h + f1), 0.0f), (float)(HH - 1));
    ow = (int)fminf(fmaxf(rintf((float)w + f2), 0.0f), (float)(WW - 1));
    lin = (od * HH + oh) * WW + ow;
}

template <bool SOA>
__device__ __forceinline__ void load3(const float* __restrict__ v, int b, int idx,
                                      float scale, float* o) {
    if constexpr (SOA) {
        int s = b * 3 * S + idx;
        o[0] = v[s] * scale; o[1] = v[s + S] * scale; o[2] = v[s + 2 * S] * scale;
    } else {
        f3 t = *(const f3*)(v + (b * S + idx) * 3);
        o[0] = t.x; o[1] = t.y; o[2] = t.z;
    }
}

// TWO squaring steps fused:  v''(p) = v'(p) + v'(r'(p)),  v'(q) = v(q) + v(r(q)).
// Gathers are exec-masked on index-identity: when the gather index equals an index
// whose value we already hold, reuse the register (bit-exact) and issue no load.
// The LSU-bytes ceiling (~10.5 B/cyc/CU) is the binding resource; masked-out lanes
// issue zero bytes.
template <bool IN_SOA, bool OUT_SOA>
__global__ __launch_bounds__(256) void fused2_k(const float* __restrict__ vin,
                                                float* __restrict__ vout,
                                                float scale) {
    // XCD-aware swizzle: each XCD owns a contiguous 1/8 slab (32 d-planes).
    int t  = blockIdx.x;
    int nb = (t >> 3) + (t & 7) * PER_XCD;
    int b  = nb / (DD * TPP);
    int r  = nb - b * (DD * TPP);
    int d  = r / TPP;
    int ip0 = (r - d * TPP) * VPB + threadIdx.x;

    int   p[K], h[K], w[K];
    float a[K][3];
    // --- stage 1: K center reads (coalesced), back-to-back ---
#pragma unroll
    for (int k = 0; k < K; ++k) {
        int ip = ip0 + k * 256;
        w[k] = ip % WW; h[k] = ip / WW;
        p[k] = d * PL + ip;
        load3<IN_SOA>(vin, b, p[k], scale, a[k]);
    }
    // --- stage 2: r0 = clamp(round(p + v(p))) ; g = v(r0), masked vs p ---
    int r0i[K];
#pragma unroll
    for (int k = 0; k < K; ++k) {
        int rd, rh, rw;
        clamp_idx(d, h[k], w[k], a[k][0], a[k][1], a[k][2], rd, rh, rw, r0i[k]);
    }
    float g[K][3];
#pragma unroll
    for (int k = 0; k < K; ++k) {
        if (r0i[k] != p[k]) {
            load3<IN_SOA>(vin, b, r0i[k], scale, g[k]);
        } else {
            g[k][0] = a[k][0]; g[k][1] = a[k][1]; g[k][2] = a[k][2];
        }
    }
    // --- stage 3: v1 = a + g ; r1 = clamp(round(p + v1)) ---
    float v1[K][3];
    int r1d[K], r1h[K], r1w[K], r1i[K];
#pragma unroll
    for (int k = 0; k < K; ++k) {
        v1[k][0] = a[k][0] + g[k][0];
        v1[k][1] = a[k][1] + g[k][1];
        v1[k][2] = a[k][2] + g[k][2];
        clamp_idx(d, h[k], w[k], v1[k][0], v1[k][1], v1[k][2],
                  r1d[k], r1h[k], r1w[k], r1i[k]);
    }
    // --- stage 4: bb = v(r1), masked vs p ---
    float bb[K][3];
#pragma unroll
    for (int k = 0; k < K; ++k) {
        if (r1i[k] != p[k]) {
            load3<IN_SOA>(vin, b, r1i[k], scale, bb[k]);
        } else {
            bb[k][0] = a[k][0]; bb[k][1] = a[k][1]; bb[k][2] = a[k][2];
        }
    }
    // --- stage 5: r2 = clamp(round(r1 + bb)) ; h2 = v(r2), masked vs r1 ---
    int r2i[K];
#pragma unroll
    for (int k = 0; k < K; ++k) {
        int rd, rh, rw;
        clamp_idx(r1d[k], r1h[k], r1w[k], bb[k][0], bb[k][1], bb[k][2],
                  rd, rh, rw, r2i[k]);
    }
    float h2[K][3];
#pragma unroll
    for (int k = 0; k < K; ++k) {
        if (r2i[k] != r1i[k]) {
            load3<IN_SOA>(vin, b, r2i[k], scale, h2[k]);
        } else {
            h2[k][0] = bb[k][0]; h2[k][1] = bb[k][1]; h2[k][2] = bb[k][2];
        }
    }
    // --- stage 6: out = v1 + (bb + h2)   [= v'(p) + v'(r1), ref grouping] ---
#pragma unroll
    for (int k = 0; k < K; ++k) {
        float o0 = v1[k][0] + (bb[k][0] + h2[k][0]);
        float o1 = v1[k][1] + (bb[k][1] + h2[k][1]);
        float o2 = v1[k][2] + (bb[k][2] + h2[k][2]);
        if constexpr (OUT_SOA) {
            int s = b * 3 * S + p[k];
            vout[s] = o0; vout[s + S] = o1; vout[s + 2 * S] = o2;
        } else {
            f3 v{o0, o1, o2};
            *(f3*)(vout + (b * S + p[k]) * 3) = v;
        }
    }
}

extern "C" void kernel_launch(void* const* d_in, const int* in_sizes, int n_in,
                              void* d_out, int out_size, void* d_ws, size_t ws_size,
                              hipStream_t stream) {
    const float* x = (const float*)d_in[0];
    float* out = (float*)d_out;     // 78,643,200 bytes — doubles as AoS intermediate
    float* ws  = (float*)d_ws;      // >= 78,643,200 bytes (tight AoS)

    // 3 fused passes (2 squaring steps each), ping-pong so the last lands in out.
    fused2_k<true,  false><<<NT, 256, 0, stream>>>(x,   out, 1.0f / 64.0f); // steps 1-2
    fused2_k<false, false><<<NT, 256, 0, stream>>>(out, ws,  1.0f);         // steps 3-4
    fused2_k<false, true ><<<NT, 256, 0, stream>>>(ws,  out, 1.0f);         // steps 5-6
}